// Round 7
// baseline (209.634 us; speedup 1.0000x reference)
//
#include <hip/hip_runtime.h>

#define N_NODES 50000
#define N_EDGES 800000
#define D 64
#define CAP 64      // bucket capacity; deg ~ Poisson(16), P(>=64) ~ 1e-26
#define BLOCK 256
#define FGRID 3125  // 3125*256 = 800000 threads = 1/edge; 12500 waves

// ---------------- fused precompute + bucket ----------------
// Requires deg[0..N_NODES*degs) zeroed beforehand (hipMemsetAsync).
// Phase 1 (per wave): M = relu(h@Wh+bh), px = (w, w*x)  -- VALU-heavy
// Phase 2 (per thread): bucket edge e by row             -- atomic-heavy
// Different waves naturally co-schedule the two pipes (m114).
__global__ __launch_bounds__(BLOCK) void pre_bucket_kernel(
    const float* __restrict__ h, const float* __restrict__ x,
    const int* __restrict__ eidx,
    const float* __restrict__ Wh, const float* __restrict__ bh,
    const float* __restrict__ Wx, const float* __restrict__ bx,
    float* __restrict__ M, float4* __restrict__ px,
    int* __restrict__ deg, int degs, int* __restrict__ adj) {
  const int lane = threadIdx.x & 63, wave = threadIdx.x >> 6;
  const int gwave = blockIdx.x * (BLOCK / 64) + wave;   // 0..12499
  const int nwaves = FGRID * (BLOCK / 64);              // 12500

  // ---- precompute: 4 nodes per wave ----
  for (int i = gwave; i < N_NODES; i += nwaves) {
    float hl = h[(size_t)i * D + lane];
    float acc = bh[lane];
#pragma unroll
    for (int k = 0; k < D; ++k)
      acc = fmaf(__shfl(hl, k), Wh[k * D + lane], acc);  // Wh L1-resident
    M[(size_t)i * D + lane] = fmaxf(acc, 0.0f);
    float wx = hl * Wx[lane];
    for (int off = 32; off > 0; off >>= 1) wx += __shfl_down(wx, off);
    if (lane == 0) {
      float w = fmaxf(wx + bx[0], 0.0f);
      px[i] = make_float4(w, w * x[i*3+0], w * x[i*3+1], w * x[i*3+2]);
    }
  }

  // ---- bucket: 1 edge per thread ----
  int e = blockIdx.x * BLOCK + threadIdx.x;
  if (e < N_EDGES) {
    int row = eidx[e];
    int col = eidx[N_EDGES + e];
    if ((unsigned)row < N_NODES && (unsigned)col < N_NODES) {
      int pos = atomicAdd(&deg[row * degs], 1);
      if (pos < CAP) adj[row * CAP + pos] = col;
    }
  }
}

// ---------------- node gather (wave/node, 4 edges in flight) ----------------

__global__ __launch_bounds__(256) void node_kernel(
    const float* __restrict__ h, const float* __restrict__ x,
    const int* __restrict__ deg, int degs, const int* __restrict__ adj,
    const float* __restrict__ M, const float4* __restrict__ px,
    float* __restrict__ out) {
  int wave = threadIdx.x >> 6, lane = threadIdx.x & 63;
  int i = blockIdx.x * 4 + wave;
  if (i >= N_NODES) return;
  int d = min(deg[i * degs], CAP);
  int g = lane >> 4, sl = lane & 15;     // g = edge slot, sl = dim quad
  const int* ai = adj + i * CAP;
  const float4* M4 = (const float4*)M;
  float4 acc  = make_float4(0.f, 0.f, 0.f, 0.f);
  float4 pacc = make_float4(0.f, 0.f, 0.f, 0.f);
#pragma unroll 2
  for (int p = g; p < d; p += 4) {
    int c = ai[p];
    float4 m4 = M4[(size_t)c * 16 + sl];
    acc.x += m4.x; acc.y += m4.y; acc.z += m4.z; acc.w += m4.w;
    if (sl == 0) {                       // one lane per group: x-path gather
      float4 pv = px[c];                 // 800KB table, L2-resident
      pacc.x += pv.x; pacc.y += pv.y; pacc.z += pv.z; pacc.w += pv.w;
    }
  }
#pragma unroll
  for (int off = 16; off <= 32; off <<= 1) {
    acc.x  += __shfl_xor(acc.x,  off); acc.y  += __shfl_xor(acc.y,  off);
    acc.z  += __shfl_xor(acc.z,  off); acc.w  += __shfl_xor(acc.w,  off);
    pacc.x += __shfl_xor(pacc.x, off); pacc.y += __shfl_xor(pacc.y, off);
    pacc.z += __shfl_xor(pacc.z, off); pacc.w += __shfl_xor(pacc.w, off);
  }
  // pacc full sum lives in the {0,16,32,48} orbit; broadcast from lane 0.
  pacc.x = __shfl(pacc.x, 0); pacc.y = __shfl(pacc.y, 0);
  pacc.z = __shfl(pacc.z, 0); pacc.w = __shfl(pacc.w, 0);

  if (g == 0) {                          // lanes 0-15: 256B coalesced h-row
    float4 hv = ((const float4*)h)[(size_t)i * 16 + sl];
    ((float4*)out)[(size_t)i * 16 + sl] =
        make_float4(hv.x + acc.x, hv.y + acc.y, hv.z + acc.z, hv.w + acc.w);
  }
  if (lane < 3) {                        // x_new = x[i]*(1+Σw) − Σ w*x[col]
    float xi = x[i * 3 + lane];
    float sw = (lane == 0) ? pacc.y : (lane == 1) ? pacc.z : pacc.w;
    out[(size_t)N_NODES * D + i * 3 + lane] = fmaf(xi, 1.0f + pacc.x, -sw);
  }
}

// ---------------- fallback (R2 atomic path, used only if ws too small) -------

__global__ __launch_bounds__(256) void init_out_kernel(
    const float* __restrict__ h, const float* __restrict__ x,
    float* __restrict__ out) {
  const int NH4 = N_NODES * D / 4;
  const int NT4 = (N_NODES * D + N_NODES * 3) / 4;
  int i = blockIdx.x * 256 + threadIdx.x;
  if (i >= NT4) return;
  float4 v;
  if (i < NH4) v = ((const float4*)h)[i];
  else         v = ((const float4*)x)[i - NH4];
  ((float4*)out)[i] = v;
}

__global__ __launch_bounds__(256) void edge_kernel(
    const float* __restrict__ h, const float* __restrict__ x,
    const int* __restrict__ eidx,
    const float* __restrict__ Wh, const float* __restrict__ bh,
    const float* __restrict__ Wx, const float* __restrict__ bx,
    float* __restrict__ out) {
  int e = blockIdx.x * 256 + threadIdx.x;
  if (e >= N_EDGES) return;
  int row = eidx[e];
  int col = eidx[N_EDGES + e];
  if ((unsigned)row >= N_NODES || (unsigned)col >= N_NODES) return;
  const float* hj = h + (size_t)col * D;
  float acc[D];
#pragma unroll
  for (int dd = 0; dd < D; ++dd) acc[dd] = bh[dd];
  float wsum = bx[0];
#pragma unroll 2
  for (int kg = 0; kg < D / 4; ++kg) {
    float4 hv = *(const float4*)(hj + kg * 4);
#pragma unroll
    for (int j = 0; j < 4; ++j) {
      float hk = (j == 0) ? hv.x : (j == 1) ? hv.y : (j == 2) ? hv.z : hv.w;
      int k = kg * 4 + j;
      wsum = fmaf(hk, Wx[k], wsum);
      const float* wrow = Wh + k * D;
#pragma unroll
      for (int dd = 0; dd < D; ++dd) acc[dd] = fmaf(hk, wrow[dd], acc[dd]);
    }
  }
  float* outh = out + (size_t)row * D;
#pragma unroll
  for (int dd = 0; dd < D; ++dd) atomicAdd(&outh[dd], fmaxf(acc[dd], 0.0f));
  float w = fmaxf(wsum, 0.0f);
  float* outx = out + (size_t)N_NODES * D + (size_t)row * 3;
  const float* xr = x + (size_t)row * 3;
  const float* xc = x + (size_t)col * 3;
#pragma unroll
  for (int c = 0; c < 3; ++c) atomicAdd(&outx[c], (xr[c] - xc[c]) * w);
}

// ---------------- launch ----------------

extern "C" void kernel_launch(void* const* d_in, const int* in_sizes, int n_in,
                              void* d_out, int out_size, void* d_ws, size_t ws_size,
                              hipStream_t stream) {
  const float* h    = (const float*)d_in[0];
  const float* x    = (const float*)d_in[1];
  const int*   eidx = (const int*)d_in[2];   // int64 in reference, int32 here
  const float* Wh   = (const float*)d_in[3];
  const float* bh   = (const float*)d_in[4];
  const float* Wx   = (const float*)d_in[5];
  const float* bx   = (const float*)d_in[6];
  float* out = (float*)d_out;

  // Pick deg padding stride by available workspace (same choice every call —
  // ws_size is fixed, so graph capture sees identical work each time).
  // DEGS=16 -> 1 counter per 64B line (29.6 MB total); DEGS=1 -> 26.6 MB.
  size_t fixed = ((size_t)N_NODES * D + 4 * N_NODES) * 4 +   // M + px
                 (size_t)N_NODES * CAP * 4;                  // adj
  int degs = (ws_size >= fixed + (size_t)N_NODES * 16 * 4) ? 16
           : (ws_size >= fixed + (size_t)N_NODES * 1 * 4)  ? 1 : 0;

  if (degs == 0) {  // fallback: atomic path (correct, slow)
    const int NT4 = (N_NODES * D + N_NODES * 3) / 4;
    init_out_kernel<<<(NT4 + 255) / 256, 256, 0, stream>>>(h, x, out);
    edge_kernel<<<(N_EDGES + 255) / 256, 256, 0, stream>>>(
        h, x, eidx, Wh, bh, Wx, bx, out);
    return;
  }

  // workspace layout (all sections 16B-aligned)
  float*  M   = (float*)d_ws;                          // 12.8 MB
  float4* px  = (float4*)(M + (size_t)N_NODES * D);    // 0.8 MB
  int*    deg = (int*)(px + N_NODES);                  // 0.2 or 3.2 MB
  int*    adj = deg + (size_t)N_NODES * degs;          // 12.8 MB

  hipMemsetAsync(deg, 0, (size_t)N_NODES * degs * sizeof(int), stream);
  pre_bucket_kernel<<<FGRID, BLOCK, 0, stream>>>(
      h, x, eidx, Wh, bh, Wx, bx, M, px, deg, degs, adj);
  node_kernel<<<(N_NODES + 3) / 4, 256, 0, stream>>>(
      h, x, deg, degs, adj, M, px, out);
}

// Round 8
// 198.237 us; speedup vs baseline: 1.0575x; 1.0575x over previous
//
#include <hip/hip_runtime.h>
#include <hip/hip_fp16.h>

#define N_NODES 50000
#define N_EDGES 800000
#define D 64
#define CAP 64      // bucket capacity; deg ~ Poisson(16), P(>=64) ~ 1e-26
#define BLOCK 256

// ---------------- precompute: M(fp16) = relu(h@Wh+bh), px = (w, w*x) --------
// Also zeroes deg[] (bucket_kernel runs after on same stream).
__global__ __launch_bounds__(BLOCK) void precompute_kernel(
    const float* __restrict__ h, const float* __restrict__ x,
    const float* __restrict__ Wh, const float* __restrict__ bh,
    const float* __restrict__ Wx, const float* __restrict__ bx,
    __half2* __restrict__ M16, float4* __restrict__ px,
    int* __restrict__ deg, int degs) {
  int tid = blockIdx.x * BLOCK + threadIdx.x;
  if (tid < N_NODES * degs) deg[tid] = 0;   // grid 12500*256=3.2M >= 800k

  int wave = threadIdx.x >> 6, lane = threadIdx.x & 63;
  int i = blockIdx.x * 4 + wave;
  if (i >= N_NODES) return;
  float hl = h[(size_t)i * D + lane];
  float acc = bh[lane];
#pragma unroll
  for (int k = 0; k < D; ++k)
    acc = fmaf(__shfl(hl, k), Wh[k * D + lane], acc);  // Wh L1-resident
  float m = fmaxf(acc, 0.0f);
  float mn = __shfl_down(m, 1);             // neighbor's element
  if (!(lane & 1))                          // even lanes pack half2
    M16[(size_t)i * 32 + (lane >> 1)] = __floats2half2_rn(m, mn);
  float wx = hl * Wx[lane];
  for (int off = 32; off > 0; off >>= 1) wx += __shfl_down(wx, off);
  if (lane == 0) {
    float w = fmaxf(wx + bx[0], 0.0f);
    px[i] = make_float4(w, w * x[i*3+0], w * x[i*3+1], w * x[i*3+2]);
  }
}

// ---------------- bucket build (R5 form: 4 VGPR, high occupancy) -----------
__global__ __launch_bounds__(256) void bucket_kernel(
    const int* __restrict__ eidx, int* __restrict__ deg, int degs,
    int* __restrict__ adj) {
  int e = blockIdx.x * 256 + threadIdx.x;
  if (e >= N_EDGES) return;
  int row = eidx[e];
  int col = eidx[N_EDGES + e];
  if ((unsigned)row >= N_NODES || (unsigned)col >= N_NODES) return;
  int pos = atomicAdd(&deg[row * degs], 1);
  if (pos < CAP) adj[row * CAP + pos] = col;
}

// ---------------- node gather: wave/node, 8 edges in flight (fp16 M) -------
__global__ __launch_bounds__(256) void node_kernel(
    const float* __restrict__ h, const float* __restrict__ x,
    const int* __restrict__ deg, int degs, const int* __restrict__ adj,
    const __half2* __restrict__ M16, const float4* __restrict__ px,
    float* __restrict__ out) {
  int wave = threadIdx.x >> 6, lane = threadIdx.x & 63;
  int i = blockIdx.x * 4 + wave;
  if (i >= N_NODES) return;
  int d = min(deg[i * degs], CAP);
  int g = lane >> 3, sl = lane & 7;        // g = edge slot (8), sl = dim octet
  const int* ai = adj + i * CAP;
  const float4* M4 = (const float4*)M16;   // 8 halves per float4; 8/row

  float a0=0,a1=0,a2=0,a3=0,a4=0,a5=0,a6=0,a7=0;
  float4 pacc = make_float4(0.f, 0.f, 0.f, 0.f);

#pragma unroll 2
  for (int p = g; p < d; p += 8) {
    int c = ai[p];                          // broadcast within group
    float4 raw = M4[(size_t)c * 8 + sl];    // 16B = 8 halves of M[c]
    const __half2* hp = (const __half2*)&raw;
    float2 q0 = __half22float2(hp[0]); a0 += q0.x; a1 += q0.y;
    float2 q1 = __half22float2(hp[1]); a2 += q1.x; a3 += q1.y;
    float2 q2 = __half22float2(hp[2]); a4 += q2.x; a5 += q2.y;
    float2 q3 = __half22float2(hp[3]); a6 += q3.x; a7 += q3.y;
    if (sl == 0) {                          // one lane/group: x-path gather
      float4 pv = px[c];                    // 800KB table, L2-resident
      pacc.x += pv.x; pacc.y += pv.y; pacc.z += pv.z; pacc.w += pv.w;
    }
  }

  // reduce the 8 edge groups: butterfly over lane bits 3,4,5
#pragma unroll
  for (int off = 8; off <= 32; off <<= 1) {
    a0 += __shfl_xor(a0, off); a1 += __shfl_xor(a1, off);
    a2 += __shfl_xor(a2, off); a3 += __shfl_xor(a3, off);
    a4 += __shfl_xor(a4, off); a5 += __shfl_xor(a5, off);
    a6 += __shfl_xor(a6, off); a7 += __shfl_xor(a7, off);
    pacc.x += __shfl_xor(pacc.x, off); pacc.y += __shfl_xor(pacc.y, off);
    pacc.z += __shfl_xor(pacc.z, off); pacc.w += __shfl_xor(pacc.w, off);
  }
  // pacc full sum lives in the {0,8,...,56} orbit; broadcast from lane 0.
  pacc.x = __shfl(pacc.x, 0); pacc.y = __shfl(pacc.y, 0);
  pacc.z = __shfl(pacc.z, 0); pacc.w = __shfl(pacc.w, 0);

  if (g == 0) {                             // lanes 0-7: dims sl*8..sl*8+7
    const float4* h4 = (const float4*)h;
    float4* o4 = (float4*)out;
    float4 hv0 = h4[(size_t)i * 16 + sl * 2];
    float4 hv1 = h4[(size_t)i * 16 + sl * 2 + 1];
    o4[(size_t)i * 16 + sl * 2] =
        make_float4(hv0.x + a0, hv0.y + a1, hv0.z + a2, hv0.w + a3);
    o4[(size_t)i * 16 + sl * 2 + 1] =
        make_float4(hv1.x + a4, hv1.y + a5, hv1.z + a6, hv1.w + a7);
  }
  if (lane < 3) {                           // x_new = x[i]*(1+Σw) − Σ w*x[col]
    float xi = x[i * 3 + lane];
    float sw = (lane == 0) ? pacc.y : (lane == 1) ? pacc.z : pacc.w;
    out[(size_t)N_NODES * D + i * 3 + lane] = fmaf(xi, 1.0f + pacc.x, -sw);
  }
}

// ---------------- fallback (R2 atomic path, used only if ws too small) -----

__global__ __launch_bounds__(256) void init_out_kernel(
    const float* __restrict__ h, const float* __restrict__ x,
    float* __restrict__ out) {
  const int NH4 = N_NODES * D / 4;
  const int NT4 = (N_NODES * D + N_NODES * 3) / 4;
  int i = blockIdx.x * 256 + threadIdx.x;
  if (i >= NT4) return;
  float4 v;
  if (i < NH4) v = ((const float4*)h)[i];
  else         v = ((const float4*)x)[i - NH4];
  ((float4*)out)[i] = v;
}

__global__ __launch_bounds__(256) void edge_kernel(
    const float* __restrict__ h, const float* __restrict__ x,
    const int* __restrict__ eidx,
    const float* __restrict__ Wh, const float* __restrict__ bh,
    const float* __restrict__ Wx, const float* __restrict__ bx,
    float* __restrict__ out) {
  int e = blockIdx.x * 256 + threadIdx.x;
  if (e >= N_EDGES) return;
  int row = eidx[e];
  int col = eidx[N_EDGES + e];
  if ((unsigned)row >= N_NODES || (unsigned)col >= N_NODES) return;
  const float* hj = h + (size_t)col * D;
  float acc[D];
#pragma unroll
  for (int dd = 0; dd < D; ++dd) acc[dd] = bh[dd];
  float wsum = bx[0];
#pragma unroll 2
  for (int kg = 0; kg < D / 4; ++kg) {
    float4 hv = *(const float4*)(hj + kg * 4);
#pragma unroll
    for (int j = 0; j < 4; ++j) {
      float hk = (j == 0) ? hv.x : (j == 1) ? hv.y : (j == 2) ? hv.z : hv.w;
      int k = kg * 4 + j;
      wsum = fmaf(hk, Wx[k], wsum);
      const float* wrow = Wh + k * D;
#pragma unroll
      for (int dd = 0; dd < D; ++dd) acc[dd] = fmaf(hk, wrow[dd], acc[dd]);
    }
  }
  float* outh = out + (size_t)row * D;
#pragma unroll
  for (int dd = 0; dd < D; ++dd) atomicAdd(&outh[dd], fmaxf(acc[dd], 0.0f));
  float w = fmaxf(wsum, 0.0f);
  float* outx = out + (size_t)N_NODES * D + (size_t)row * 3;
  const float* xr = x + (size_t)row * 3;
  const float* xc = x + (size_t)col * 3;
#pragma unroll
  for (int c = 0; c < 3; ++c) atomicAdd(&outx[c], (xr[c] - xc[c]) * w);
}

// ---------------- launch ----------------

extern "C" void kernel_launch(void* const* d_in, const int* in_sizes, int n_in,
                              void* d_out, int out_size, void* d_ws, size_t ws_size,
                              hipStream_t stream) {
  const float* h    = (const float*)d_in[0];
  const float* x    = (const float*)d_in[1];
  const int*   eidx = (const int*)d_in[2];   // int64 in reference, int32 here
  const float* Wh   = (const float*)d_in[3];
  const float* bh   = (const float*)d_in[4];
  const float* Wx   = (const float*)d_in[5];
  const float* bx   = (const float*)d_in[6];
  float* out = (float*)d_out;

  // deg padding stride chosen by fixed ws_size (same choice every call).
  size_t fixed = (size_t)N_NODES * D * 2 +          // M16 (fp16)   6.4 MB
                 (size_t)N_NODES * 16 +             // px           0.8 MB
                 (size_t)N_NODES * CAP * 4;         // adj         12.8 MB
  int degs = (ws_size >= fixed + (size_t)N_NODES * 16 * 4) ? 16
           : (ws_size >= fixed + (size_t)N_NODES * 1 * 4)  ? 1 : 0;

  if (degs == 0) {  // fallback: atomic path (correct, slow)
    const int NT4 = (N_NODES * D + N_NODES * 3) / 4;
    init_out_kernel<<<(NT4 + 255) / 256, 256, 0, stream>>>(h, x, out);
    edge_kernel<<<(N_EDGES + 255) / 256, 256, 0, stream>>>(
        h, x, eidx, Wh, bh, Wx, bx, out);
    return;
  }

  // workspace layout (all sections 16B-aligned)
  __half2* M16 = (__half2*)d_ws;                              // 6.4 MB
  float4*  px  = (float4*)((char*)d_ws + (size_t)N_NODES * D * 2);
  int*     deg = (int*)(px + N_NODES);
  int*     adj = deg + (size_t)N_NODES * degs;

  const int NB4 = (N_NODES + 3) / 4;       // 12500
  const int EB  = (N_EDGES + 255) / 256;   // 3125

  precompute_kernel<<<NB4, BLOCK, 0, stream>>>(
      h, x, Wh, bh, Wx, bx, M16, px, deg, degs);
  bucket_kernel<<<EB, 256, 0, stream>>>(eidx, deg, degs, adj);
  node_kernel<<<NB4, 256, 0, stream>>>(
      h, x, deg, degs, adj, M16, px, out);
}

// Round 9
// 150.274 us; speedup vs baseline: 1.3950x; 1.3192x over previous
//
#include <hip/hip_runtime.h>
#include <hip/hip_fp16.h>

#define N_NODES 50000
#define N_EDGES 800000
#define D 64
#define CAP 64      // bucket capacity; deg ~ Poisson(16), P(>=64) ~ 1e-26
#define BLOCK 256
#define MGRID 15625 // 12500 precompute blocks + 3125 bucket blocks, interleaved

// ---------- merged precompute | bucket (block-split, co-resident) ----------
// Blocks with (b+1)%5==0 run the bucket path (256 edges each, atomic-heavy,
// ~0.5% VALU); the other 12500 blocks run precompute (VALU-heavy). Disjoint
// block populations co-schedule on the same CUs -> VALU work hides under
// memory-side atomic latency (m114). deg must be zeroed beforehand (memset).
__global__ __launch_bounds__(BLOCK) void pre_bucket_kernel(
    const float* __restrict__ h, const float* __restrict__ x,
    const int* __restrict__ eidx,
    const float* __restrict__ Wh, const float* __restrict__ bh,
    const float* __restrict__ Wx, const float* __restrict__ bx,
    __half2* __restrict__ M16, float4* __restrict__ px,
    int* __restrict__ deg, int* __restrict__ adj) {
  const unsigned b = blockIdx.x;

  if ((b + 1) % 5u == 0) {             // ---- bucket path ----
    int bid = (int)((b + 1) / 5u) - 1; // 0..3124
    int e = bid * BLOCK + threadIdx.x;
    if (e < N_EDGES) {
      int row = eidx[e];
      int col = eidx[N_EDGES + e];
      if ((unsigned)row < N_NODES && (unsigned)col < N_NODES) {
        int pos = atomicAdd(&deg[row], 1);
        if (pos < CAP) adj[row * CAP + pos] = col;
      }
    }
    return;
  }

  // ---- precompute path: M(fp16) = relu(h@Wh+bh), px = (w, w*x) ----
  int pid = (int)(b - (b + 1) / 5u);   // 0..12499
  int wave = threadIdx.x >> 6, lane = threadIdx.x & 63;
  int i = pid * 4 + wave;
  if (i >= N_NODES) return;
  float hl = h[(size_t)i * D + lane];
  float acc = bh[lane];
#pragma unroll
  for (int k = 0; k < D; ++k)
    acc = fmaf(__shfl(hl, k), Wh[k * D + lane], acc);  // Wh L1-resident
  float m = fmaxf(acc, 0.0f);
  float mn = __shfl_down(m, 1);
  if (!(lane & 1))                     // even lanes pack half2
    M16[(size_t)i * 32 + (lane >> 1)] = __floats2half2_rn(m, mn);
  float wx = hl * Wx[lane];
  for (int off = 32; off > 0; off >>= 1) wx += __shfl_down(wx, off);
  if (lane == 0) {
    float w = fmaxf(wx + bx[0], 0.0f);
    px[i] = make_float4(w, w * x[i*3+0], w * x[i*3+1], w * x[i*3+2]);
  }
}

// ---------- node gather: wave handles 2 nodes (independent chains) ----------
__global__ __launch_bounds__(256) void node_kernel(
    const float* __restrict__ h, const float* __restrict__ x,
    const int* __restrict__ deg, const int* __restrict__ adj,
    const __half2* __restrict__ M16, const float4* __restrict__ px,
    float* __restrict__ out) {
  int wave = threadIdx.x >> 6, lane = threadIdx.x & 63;
  int gw = blockIdx.x * 4 + wave;      // 0..24999
  int i0 = gw * 2;
  if (i0 >= N_NODES) return;
  int i1 = i0 + 1;                     // N_NODES even -> always valid
  int g = lane >> 3, sl = lane & 7;    // g = edge slot (8), sl = dim octet
  int d0 = min(deg[i0], CAP), d1 = min(deg[i1], CAP);
  const int* a0 = adj + i0 * CAP;
  const int* a1 = adj + i1 * CAP;
  const float4* M4 = (const float4*)M16;  // 16B = 8 halves; 8 per M row

  float s0[8] = {0,0,0,0,0,0,0,0}, s1[8] = {0,0,0,0,0,0,0,0};
  float4 p0 = make_float4(0,0,0,0), p1 = make_float4(0,0,0,0);

  int dmax = max(d0, d1);
  for (int p = g; p < dmax; p += 8) {
    if (p < d0) {
      int c = a0[p];
      float4 raw = M4[(size_t)c * 8 + sl];
      const __half2* hp = (const __half2*)&raw;
      float2 q0 = __half22float2(hp[0]); s0[0] += q0.x; s0[1] += q0.y;
      float2 q1 = __half22float2(hp[1]); s0[2] += q1.x; s0[3] += q1.y;
      float2 q2 = __half22float2(hp[2]); s0[4] += q2.x; s0[5] += q2.y;
      float2 q3 = __half22float2(hp[3]); s0[6] += q3.x; s0[7] += q3.y;
      if (sl == 0) {
        float4 pv = px[c];
        p0.x += pv.x; p0.y += pv.y; p0.z += pv.z; p0.w += pv.w;
      }
    }
    if (p < d1) {
      int c = a1[p];
      float4 raw = M4[(size_t)c * 8 + sl];
      const __half2* hp = (const __half2*)&raw;
      float2 q0 = __half22float2(hp[0]); s1[0] += q0.x; s1[1] += q0.y;
      float2 q1 = __half22float2(hp[1]); s1[2] += q1.x; s1[3] += q1.y;
      float2 q2 = __half22float2(hp[2]); s1[4] += q2.x; s1[5] += q2.y;
      float2 q3 = __half22float2(hp[3]); s1[6] += q3.x; s1[7] += q3.y;
      if (sl == 0) {
        float4 pv = px[c];
        p1.x += pv.x; p1.y += pv.y; p1.z += pv.z; p1.w += pv.w;
      }
    }
  }

  // allreduce over the 8 edge groups (lane bits 3,4,5). sl-lanes only mix
  // with same-sl lanes, so acc sums land in every lane; pacc sums land in
  // all sl==0 lanes (orbit {0,8,..,56}).
#pragma unroll
  for (int off = 8; off <= 32; off <<= 1) {
#pragma unroll
    for (int q = 0; q < 8; ++q) {
      s0[q] += __shfl_xor(s0[q], off);
      s1[q] += __shfl_xor(s1[q], off);
    }
    p0.x += __shfl_xor(p0.x, off); p0.y += __shfl_xor(p0.y, off);
    p0.z += __shfl_xor(p0.z, off); p0.w += __shfl_xor(p0.w, off);
    p1.x += __shfl_xor(p1.x, off); p1.y += __shfl_xor(p1.y, off);
    p1.z += __shfl_xor(p1.z, off); p1.w += __shfl_xor(p1.w, off);
  }
  p0.x = __shfl(p0.x, 0); p0.y = __shfl(p0.y, 0);
  p0.z = __shfl(p0.z, 0); p0.w = __shfl(p0.w, 0);
  p1.x = __shfl(p1.x, 0); p1.y = __shfl(p1.y, 0);
  p1.z = __shfl(p1.z, 0); p1.w = __shfl(p1.w, 0);

  const float4* h4 = (const float4*)h;
  float4* o4 = (float4*)out;
  if (g == 0) {                        // lanes 0-7: node i0 h-row (256B)
    float4 hv0 = h4[(size_t)i0 * 16 + sl * 2];
    float4 hv1 = h4[(size_t)i0 * 16 + sl * 2 + 1];
    o4[(size_t)i0 * 16 + sl * 2] =
        make_float4(hv0.x + s0[0], hv0.y + s0[1], hv0.z + s0[2], hv0.w + s0[3]);
    o4[(size_t)i0 * 16 + sl * 2 + 1] =
        make_float4(hv1.x + s0[4], hv1.y + s0[5], hv1.z + s0[6], hv1.w + s0[7]);
  } else if (g == 1) {                 // lanes 8-15: node i1 h-row
    float4 hv0 = h4[(size_t)i1 * 16 + sl * 2];
    float4 hv1 = h4[(size_t)i1 * 16 + sl * 2 + 1];
    o4[(size_t)i1 * 16 + sl * 2] =
        make_float4(hv0.x + s1[0], hv0.y + s1[1], hv0.z + s1[2], hv0.w + s1[3]);
    o4[(size_t)i1 * 16 + sl * 2 + 1] =
        make_float4(hv1.x + s1[4], hv1.y + s1[5], hv1.z + s1[6], hv1.w + s1[7]);
  }
  const size_t xbase = (size_t)N_NODES * D;
  if (lane < 3) {                      // x_new[i0]
    float xi = x[i0 * 3 + lane];
    float sw = (lane == 0) ? p0.y : (lane == 1) ? p0.z : p0.w;
    out[xbase + i0 * 3 + lane] = fmaf(xi, 1.0f + p0.x, -sw);
  } else if (g == 1 && sl < 3) {       // x_new[i1]
    float xi = x[i1 * 3 + sl];
    float sw = (sl == 0) ? p1.y : (sl == 1) ? p1.z : p1.w;
    out[xbase + i1 * 3 + sl] = fmaf(xi, 1.0f + p1.x, -sw);
  }
}

// ---------------- fallback (R2 atomic path, used only if ws too small) -----

__global__ __launch_bounds__(256) void init_out_kernel(
    const float* __restrict__ h, const float* __restrict__ x,
    float* __restrict__ out) {
  const int NH4 = N_NODES * D / 4;
  const int NT4 = (N_NODES * D + N_NODES * 3) / 4;
  int i = blockIdx.x * 256 + threadIdx.x;
  if (i >= NT4) return;
  float4 v;
  if (i < NH4) v = ((const float4*)h)[i];
  else         v = ((const float4*)x)[i - NH4];
  ((float4*)out)[i] = v;
}

__global__ __launch_bounds__(256) void edge_kernel(
    const float* __restrict__ h, const float* __restrict__ x,
    const int* __restrict__ eidx,
    const float* __restrict__ Wh, const float* __restrict__ bh,
    const float* __restrict__ Wx, const float* __restrict__ bx,
    float* __restrict__ out) {
  int e = blockIdx.x * 256 + threadIdx.x;
  if (e >= N_EDGES) return;
  int row = eidx[e];
  int col = eidx[N_EDGES + e];
  if ((unsigned)row >= N_NODES || (unsigned)col >= N_NODES) return;
  const float* hj = h + (size_t)col * D;
  float acc[D];
#pragma unroll
  for (int dd = 0; dd < D; ++dd) acc[dd] = bh[dd];
  float wsum = bx[0];
#pragma unroll 2
  for (int kg = 0; kg < D / 4; ++kg) {
    float4 hv = *(const float4*)(hj + kg * 4);
#pragma unroll
    for (int j = 0; j < 4; ++j) {
      float hk = (j == 0) ? hv.x : (j == 1) ? hv.y : (j == 2) ? hv.z : hv.w;
      int k = kg * 4 + j;
      wsum = fmaf(hk, Wx[k], wsum);
      const float* wrow = Wh + k * D;
#pragma unroll
      for (int dd = 0; dd < D; ++dd) acc[dd] = fmaf(hk, wrow[dd], acc[dd]);
    }
  }
  float* outh = out + (size_t)row * D;
#pragma unroll
  for (int dd = 0; dd < D; ++dd) atomicAdd(&outh[dd], fmaxf(acc[dd], 0.0f));
  float w = fmaxf(wsum, 0.0f);
  float* outx = out + (size_t)N_NODES * D + (size_t)row * 3;
  const float* xr = x + (size_t)row * 3;
  const float* xc = x + (size_t)col * 3;
#pragma unroll
  for (int c = 0; c < 3; ++c) atomicAdd(&outx[c], (xr[c] - xc[c]) * w);
}

// ---------------- launch ----------------

extern "C" void kernel_launch(void* const* d_in, const int* in_sizes, int n_in,
                              void* d_out, int out_size, void* d_ws, size_t ws_size,
                              hipStream_t stream) {
  const float* h    = (const float*)d_in[0];
  const float* x    = (const float*)d_in[1];
  const int*   eidx = (const int*)d_in[2];   // int64 in reference, int32 here
  const float* Wh   = (const float*)d_in[3];
  const float* bh   = (const float*)d_in[4];
  const float* Wx   = (const float*)d_in[5];
  const float* bx   = (const float*)d_in[6];
  float* out = (float*)d_out;

  // workspace: M16 6.4MB | px 0.8MB | deg 0.2MB | adj 12.8MB  (~20.2MB)
  size_t need = (size_t)N_NODES * D * 2 + (size_t)N_NODES * 16 +
                (size_t)N_NODES * 4 + (size_t)N_NODES * CAP * 4;

  if (ws_size < need) {  // fallback: atomic path (correct, slow)
    const int NT4 = (N_NODES * D + N_NODES * 3) / 4;
    init_out_kernel<<<(NT4 + 255) / 256, 256, 0, stream>>>(h, x, out);
    edge_kernel<<<(N_EDGES + 255) / 256, 256, 0, stream>>>(
        h, x, eidx, Wh, bh, Wx, bx, out);
    return;
  }

  __half2* M16 = (__half2*)d_ws;
  float4*  px  = (float4*)((char*)d_ws + (size_t)N_NODES * D * 2);
  int*     deg = (int*)(px + N_NODES);
  int*     adj = deg + N_NODES;

  hipMemsetAsync(deg, 0, (size_t)N_NODES * sizeof(int), stream);
  pre_bucket_kernel<<<MGRID, BLOCK, 0, stream>>>(
      h, x, eidx, Wh, bh, Wx, bx, M16, px, deg, adj);
  node_kernel<<<(N_NODES + 7) / 8, 256, 0, stream>>>(
      h, x, deg, adj, M16, px, out);
}